// Round 1
// baseline (1682.274 us; speedup 1.0000x reference)
//
#include <hip/hip_runtime.h>

// ---------------- CSR build ----------------
__global__ __launch_bounds__(256) void hist_kernel(
    const int* __restrict__ src, const int* __restrict__ dst, int E,
    int* __restrict__ deg_u, int* __restrict__ deg_m)
{
    int i = blockIdx.x * 256 + threadIdx.x;
    if (i < E) {
        atomicAdd(&deg_m[dst[i]], 1);
        atomicAdd(&deg_u[src[i]], 1);
    }
}

__global__ __launch_bounds__(256) void scan_k1(
    const int* __restrict__ in, int n, int* __restrict__ bsum)
{
    __shared__ int tmp[256];
    int t = threadIdx.x, b = blockIdx.x;
    int i = b * 256 + t;
    tmp[t] = (i < n) ? in[i] : 0;
    __syncthreads();
    for (int d = 128; d > 0; d >>= 1) {
        if (t < d) tmp[t] += tmp[t + d];
        __syncthreads();
    }
    if (t == 0) bsum[b] = tmp[0];
}

__global__ __launch_bounds__(1024) void scan_k2(int* bsum, int nb)
{
    __shared__ int tmp[1024];
    int t = threadIdx.x;
    int v = (t < nb) ? bsum[t] : 0;
    tmp[t] = v;
    __syncthreads();
    for (int d = 1; d < 1024; d <<= 1) {
        int x = (t >= d) ? tmp[t - d] : 0;
        __syncthreads();
        tmp[t] += x;
        __syncthreads();
    }
    if (t < nb) bsum[t] = tmp[t] - v;  // exclusive
}

__global__ __launch_bounds__(256) void scan_k3(
    const int* __restrict__ in, int n, const int* __restrict__ bsum,
    int* __restrict__ off)
{
    __shared__ int tmp[256];
    int t = threadIdx.x, b = blockIdx.x;
    int i = b * 256 + t;
    int v = (i < n) ? in[i] : 0;
    tmp[t] = v;
    __syncthreads();
    for (int d = 1; d < 256; d <<= 1) {
        int x = (t >= d) ? tmp[t - d] : 0;
        __syncthreads();
        tmp[t] += x;
        __syncthreads();
    }
    if (i < n) off[i] = bsum[b] + tmp[t] - v;
    if (i == n - 1) off[n] = bsum[b] + tmp[t];
}

__global__ __launch_bounds__(256) void place_kernel(
    const int* __restrict__ src, const int* __restrict__ dst, int E,
    const int* __restrict__ off_m, int* __restrict__ cur_m, int* __restrict__ csr_m_src,
    const int* __restrict__ off_u, int* __restrict__ cur_u, int* __restrict__ csr_u_dst)
{
    int i = blockIdx.x * 256 + threadIdx.x;
    if (i < E) {
        int s = src[i], d = dst[i];
        int pm = off_m[d] + atomicAdd(&cur_m[d], 1);
        csr_m_src[pm] = s;
        int pu = off_u[s] + atomicAdd(&cur_u[s], 1);
        csr_u_dst[pu] = d;
    }
}

// ---------------- tiled GEMM: Y[M,64] = X[M,K] @ W[K,64] ----------------
template<int K>
__global__ __launch_bounds__(256) void gemm_tile(
    const float* __restrict__ X, const float* __restrict__ W,
    float* __restrict__ Y, int M)
{
    __shared__ float Ws[K * 64];
    __shared__ float Xs[K][68];   // k-major, padded (stride 68 words: 16B-aligned float4 rows)
    int tid = threadIdx.x;
    int row0 = blockIdx.x * 64;
    for (int i = tid; i < K * 64; i += 256) Ws[i] = W[i];
    for (int i = tid; i < 64 * K; i += 256) {
        int r = i / K, k = i - r * K;
        int gr = row0 + r;
        Xs[k][r] = (gr < M) ? X[gr * K + k] : 0.f;
    }
    __syncthreads();
    int tr = (tid & 15) * 4;   // 4 rows
    int tc = (tid >> 4) * 4;   // 4 cols
    float acc[4][4] = {};
#pragma unroll 8
    for (int k = 0; k < K; ++k) {
        float4 xv = *(const float4*)&Xs[k][tr];
        float4 wv = *(const float4*)&Ws[k * 64 + tc];
        acc[0][0] += xv.x * wv.x; acc[0][1] += xv.x * wv.y; acc[0][2] += xv.x * wv.z; acc[0][3] += xv.x * wv.w;
        acc[1][0] += xv.y * wv.x; acc[1][1] += xv.y * wv.y; acc[1][2] += xv.y * wv.z; acc[1][3] += xv.y * wv.w;
        acc[2][0] += xv.z * wv.x; acc[2][1] += xv.z * wv.y; acc[2][2] += xv.z * wv.z; acc[2][3] += xv.z * wv.w;
        acc[3][0] += xv.w * wv.x; acc[3][1] += xv.w * wv.y; acc[3][2] += xv.w * wv.z; acc[3][3] += xv.w * wv.w;
    }
#pragma unroll
    for (int r = 0; r < 4; ++r) {
        int gr = row0 + tr + r;
        if (gr < M) {
            float4 o = make_float4(acc[r][0], acc[r][1], acc[r][2], acc[r][3]);
            *(float4*)&Y[gr * 64 + tc] = o;
        }
    }
}

// ---------------- CSR mean-aggregate + bias + self-term (+relu) ----------------
// out[n, lane] = relu?( mean_{p in [off[n],off[n+1])} a[csr[p], lane] + bias[lane] + c[n, lane] )
__global__ __launch_bounds__(256) void agg_kernel(
    const float* __restrict__ a, const float* __restrict__ c,
    const float* __restrict__ bias,
    const int* __restrict__ off, const int* __restrict__ csr,
    float* __restrict__ out, int n_dst, int do_relu)
{
    int node = blockIdx.x * 4 + (threadIdx.x >> 6);
    if (node >= n_dst) return;
    int lane = threadIdx.x & 63;
    int beg = off[node], end = off[node + 1];
    float acc = 0.f;
    int p = beg;
    for (; p + 4 <= end; p += 4) {
        int s0 = csr[p], s1 = csr[p + 1], s2 = csr[p + 2], s3 = csr[p + 3];
        acc += a[s0 * 64 + lane];
        acc += a[s1 * 64 + lane];
        acc += a[s2 * 64 + lane];
        acc += a[s3 * 64 + lane];
    }
    for (; p < end; ++p) acc += a[csr[p] * 64 + lane];
    int deg = end - beg;
    float inv = 1.f / (float)(deg > 0 ? deg : 1);
    float v = acc * inv + bias[lane] + c[node * 64 + lane];
    if (do_relu) v = fmaxf(v, 0.f);
    out[node * 64 + lane] = v;
}

// ---------------- decoder: gather-concat -> GEMM(128x64) -> relu -> @Wd2 + bd2 ----------------
__global__ __launch_bounds__(256) void decoder_kernel(
    const float* __restrict__ z_u, const float* __restrict__ z_m,
    const int* __restrict__ ls, const int* __restrict__ ld,
    const float* __restrict__ Wd1, const float* __restrict__ bd1,
    const float* __restrict__ Wd2, const float* __restrict__ bd2,
    float* __restrict__ out, int L)
{
    __shared__ float Ws[128 * 64];
    __shared__ float Xs[128][68];
    __shared__ float red[64][17];
    int tid = threadIdx.x;
    int row0 = blockIdx.x * 64;
    for (int i = tid; i < 128 * 64; i += 256) Ws[i] = Wd1[i];
    for (int i = tid; i < 64 * 128; i += 256) {
        int r = i >> 7, k = i & 127;
        int gr = row0 + r;
        float v = 0.f;
        if (gr < L) {
            if (k < 64) v = z_u[ls[gr] * 64 + k];
            else        v = z_m[ld[gr] * 64 + (k - 64)];
        }
        Xs[k][r] = v;
    }
    __syncthreads();
    int tr = (tid & 15) * 4;
    int tc = (tid >> 4) * 4;
    float acc[4][4] = {};
#pragma unroll 8
    for (int k = 0; k < 128; ++k) {
        float4 xv = *(const float4*)&Xs[k][tr];
        float4 wv = *(const float4*)&Ws[k * 64 + tc];
        acc[0][0] += xv.x * wv.x; acc[0][1] += xv.x * wv.y; acc[0][2] += xv.x * wv.z; acc[0][3] += xv.x * wv.w;
        acc[1][0] += xv.y * wv.x; acc[1][1] += xv.y * wv.y; acc[1][2] += xv.y * wv.z; acc[1][3] += xv.y * wv.w;
        acc[2][0] += xv.z * wv.x; acc[2][1] += xv.z * wv.y; acc[2][2] += xv.z * wv.z; acc[2][3] += xv.z * wv.w;
        acc[3][0] += xv.w * wv.x; acc[3][1] += xv.w * wv.y; acc[3][2] += xv.w * wv.z; acc[3][3] += xv.w * wv.w;
    }
    float b1v[4], w2v[4];
#pragma unroll
    for (int ci = 0; ci < 4; ++ci) { b1v[ci] = bd1[tc + ci]; w2v[ci] = Wd2[tc + ci]; }
    int g = tid >> 4;
#pragma unroll
    for (int r = 0; r < 4; ++r) {
        float s = 0.f;
#pragma unroll
        for (int ci = 0; ci < 4; ++ci) {
            float tv = acc[r][ci] + b1v[ci];
            tv = fmaxf(tv, 0.f);
            s += tv * w2v[ci];
        }
        red[tr + r][g] = s;
    }
    __syncthreads();
    if (tid < 64) {
        int gr = row0 + tid;
        if (gr < L) {
            float s = bd2[0];
#pragma unroll
            for (int g2 = 0; g2 < 16; ++g2) s += red[tid][g2];
            out[gr] = s;
        }
    }
}

// ---------------- host launcher ----------------
extern "C" void kernel_launch(void* const* d_in, const int* in_sizes, int n_in,
                              void* d_out, int out_size, void* d_ws, size_t ws_size,
                              hipStream_t stream)
{
    const float* x_user  = (const float*)d_in[0];
    const float* x_movie = (const float*)d_in[1];
    const int*   esrc    = (const int*)d_in[2];
    const int*   edst    = (const int*)d_in[3];
    const int*   lsrc    = (const int*)d_in[4];
    const int*   ldst    = (const int*)d_in[5];
    const float* W1ul = (const float*)d_in[6];
    const float* b1u  = (const float*)d_in[7];
    const float* W1ur = (const float*)d_in[8];
    const float* W1ml = (const float*)d_in[9];
    const float* b1m  = (const float*)d_in[10];
    const float* W1mr = (const float*)d_in[11];
    const float* W2ul = (const float*)d_in[12];
    const float* b2u  = (const float*)d_in[13];
    const float* W2ur = (const float*)d_in[14];
    const float* W2ml = (const float*)d_in[15];
    const float* b2m  = (const float*)d_in[16];
    const float* W2mr = (const float*)d_in[17];
    const float* Wd1  = (const float*)d_in[18];
    const float* bd1  = (const float*)d_in[19];
    const float* Wd2  = (const float*)d_in[20];
    const float* bd2  = (const float*)d_in[21];
    float* out = (float*)d_out;

    const int NU = in_sizes[0] / 128;
    const int NM = in_sizes[1] / 128;
    const int E  = in_sizes[2];
    const int L  = in_sizes[4];

    // workspace layout (all offsets 256B-aligned)
    char* ws = (char*)d_ws;
    const size_t SU = (size_t)NU * 64 * 4;   // 51.2 MB
    const size_t SM = (size_t)NM * 64 * 4;   // 20.48 MB
    float* U0 = (float*)(ws + 0);
    float* U1 = (float*)(ws + SU);
    float* U2 = (float*)(ws + 2 * SU);
    float* M0 = (float*)(ws + 3 * SU);
    float* M1 = (float*)(ws + 3 * SU + SM);
    float* M2 = (float*)(ws + 3 * SU + 2 * SM);
    size_t o = 3 * SU + 3 * SM;
    auto align256 = [](size_t x) { return (x + 255) & ~(size_t)255; };
    int* off_u = (int*)(ws + o); o = align256(o + (size_t)(NU + 1) * 4);
    int* off_m = (int*)(ws + o); o = align256(o + (size_t)(NM + 1) * 4);
    int* deg_u = (int*)(ws + o); o = align256(o + (size_t)NU * 4);
    int* deg_m = (int*)(ws + o); o = align256(o + (size_t)NM * 4);
    int* cur_u = (int*)(ws + o); o = align256(o + (size_t)NU * 4);
    int* cur_m = (int*)(ws + o); o = align256(o + (size_t)NM * 4);
    int* bsum  = (int*)(ws + o); o = align256(o + 4096);
    int* csr_m_src = (int*)(ws + o); o = align256(o + (size_t)E * 4);
    int* csr_u_dst = (int*)(ws + o); o = align256(o + (size_t)E * 4);

    // ---- CSR build ----
    hipMemsetAsync(deg_u, 0, (size_t)NU * 4, stream);
    hipMemsetAsync(deg_m, 0, (size_t)NM * 4, stream);
    hipMemsetAsync(cur_u, 0, (size_t)NU * 4, stream);
    hipMemsetAsync(cur_m, 0, (size_t)NM * 4, stream);
    int egrid = (E + 255) / 256;
    hist_kernel<<<egrid, 256, 0, stream>>>(esrc, edst, E, deg_u, deg_m);

    int nb_u = (NU + 255) / 256;
    scan_k1<<<nb_u, 256, 0, stream>>>(deg_u, NU, bsum);
    scan_k2<<<1, 1024, 0, stream>>>(bsum, nb_u);
    scan_k3<<<nb_u, 256, 0, stream>>>(deg_u, NU, bsum, off_u);

    int nb_m = (NM + 255) / 256;
    scan_k1<<<nb_m, 256, 0, stream>>>(deg_m, NM, bsum);
    scan_k2<<<1, 1024, 0, stream>>>(bsum, nb_m);
    scan_k3<<<nb_m, 256, 0, stream>>>(deg_m, NM, bsum, off_m);

    place_kernel<<<egrid, 256, 0, stream>>>(esrc, edst, E, off_m, cur_m, csr_m_src,
                                            off_u, cur_u, csr_u_dst);

    int gu = (NU + 63) / 64, gm = (NM + 63) / 64;

    // ---- layer 1: pre-multiplied tables + self terms ----
    gemm_tile<128><<<gu, 256, 0, stream>>>(x_user,  W1ul, U0, NU);  // a_u
    gemm_tile<128><<<gu, 256, 0, stream>>>(x_user,  W1mr, U1, NU);  // c_u
    gemm_tile<128><<<gm, 256, 0, stream>>>(x_movie, W1ml, M0, NM);  // a_m
    gemm_tile<128><<<gm, 256, 0, stream>>>(x_movie, W1ur, M1, NM);  // c_m

    int agm = (NM + 3) / 4, agu = (NU + 3) / 4;
    agg_kernel<<<agm, 256, 0, stream>>>(U0, M1, b1u, off_m, csr_m_src, M2, NM, 1); // h_m
    agg_kernel<<<agu, 256, 0, stream>>>(M0, U1, b1m, off_u, csr_u_dst, U2, NU, 1); // h_u

    // ---- layer 2 ----
    gemm_tile<64><<<gu, 256, 0, stream>>>(U2, W2ul, U0, NU);  // p_u = h_u @ W2_u2m_l
    gemm_tile<64><<<gu, 256, 0, stream>>>(U2, W2mr, U1, NU);  // q_u = h_u @ W2_m2u_r
    gemm_tile<64><<<gm, 256, 0, stream>>>(M2, W2ml, M0, NM);  // p_m = h_m @ W2_m2u_l
    gemm_tile<64><<<gm, 256, 0, stream>>>(M2, W2ur, M1, NM);  // q_m = h_m @ W2_u2m_r

    agg_kernel<<<agm, 256, 0, stream>>>(U0, M1, b2u, off_m, csr_m_src, M2, NM, 0); // z_m
    agg_kernel<<<agu, 256, 0, stream>>>(M0, U1, b2m, off_u, csr_u_dst, U2, NU, 0); // z_u

    // ---- decoder ----
    int gl = (L + 63) / 64;
    decoder_kernel<<<gl, 256, 0, stream>>>(U2, M2, lsrc, ldst, Wd1, bd1, Wd2, bd2, out, L);
}

// Round 2
// 1473.996 us; speedup vs baseline: 1.1413x; 1.1413x over previous
//
#include <hip/hip_runtime.h>

// ---------------- CSR build ----------------
__global__ __launch_bounds__(256) void hist_kernel(
    const int* __restrict__ src, const int* __restrict__ dst, int E,
    int* __restrict__ deg_u, int* __restrict__ deg_m)
{
    int i = blockIdx.x * 256 + threadIdx.x;
    if (i < E) {
        atomicAdd(&deg_m[dst[i]], 1);
        atomicAdd(&deg_u[src[i]], 1);
    }
}

__global__ __launch_bounds__(256) void scan_k1(
    const int* __restrict__ in, int n, int* __restrict__ bsum)
{
    __shared__ int tmp[256];
    int t = threadIdx.x, b = blockIdx.x;
    int i = b * 256 + t;
    tmp[t] = (i < n) ? in[i] : 0;
    __syncthreads();
    for (int d = 128; d > 0; d >>= 1) {
        if (t < d) tmp[t] += tmp[t + d];
        __syncthreads();
    }
    if (t == 0) bsum[b] = tmp[0];
}

__global__ __launch_bounds__(1024) void scan_k2(int* bsum, int nb)
{
    __shared__ int tmp[1024];
    int t = threadIdx.x;
    int v = (t < nb) ? bsum[t] : 0;
    tmp[t] = v;
    __syncthreads();
    for (int d = 1; d < 1024; d <<= 1) {
        int x = (t >= d) ? tmp[t - d] : 0;
        __syncthreads();
        tmp[t] += x;
        __syncthreads();
    }
    if (t < nb) bsum[t] = tmp[t] - v;  // exclusive
}

__global__ __launch_bounds__(256) void scan_k3(
    const int* __restrict__ in, int n, const int* __restrict__ bsum,
    int* __restrict__ off)
{
    __shared__ int tmp[256];
    int t = threadIdx.x, b = blockIdx.x;
    int i = b * 256 + t;
    int v = (i < n) ? in[i] : 0;
    tmp[t] = v;
    __syncthreads();
    for (int d = 1; d < 256; d <<= 1) {
        int x = (t >= d) ? tmp[t - d] : 0;
        __syncthreads();
        tmp[t] += x;
        __syncthreads();
    }
    if (i < n) off[i] = bsum[b] + tmp[t] - v;
    if (i == n - 1) off[n] = bsum[b] + tmp[t];
}

__global__ __launch_bounds__(256) void place_kernel(
    const int* __restrict__ src, const int* __restrict__ dst, int E,
    const int* __restrict__ off_m, int* __restrict__ cur_m, int* __restrict__ csr_m_src,
    const int* __restrict__ off_u, int* __restrict__ cur_u, int* __restrict__ csr_u_dst)
{
    int i = blockIdx.x * 256 + threadIdx.x;
    if (i < E) {
        int s = src[i], d = dst[i];
        int pm = off_m[d] + atomicAdd(&cur_m[d], 1);
        csr_m_src[pm] = s;
        int pu = off_u[s] + atomicAdd(&cur_u[s], 1);
        csr_u_dst[pu] = d;
    }
}

// ---------------- tiled GEMM: Y[M,64] = X[M,K] @ W[K,64] ----------------
template<int K>
__global__ __launch_bounds__(256) void gemm_tile(
    const float* __restrict__ X, const float* __restrict__ W,
    float* __restrict__ Y, int M)
{
    __shared__ float Ws[K * 64];
    __shared__ float Xs[K][68];   // k-major, padded (16B-aligned float4 rows)
    int tid = threadIdx.x;
    int row0 = blockIdx.x * 64;
    for (int i = tid; i < K * 64; i += 256) Ws[i] = W[i];
    for (int i = tid; i < 64 * K; i += 256) {
        int r = i / K, k = i - r * K;
        int gr = row0 + r;
        Xs[k][r] = (gr < M) ? X[gr * K + k] : 0.f;
    }
    __syncthreads();
    int tr = (tid & 15) * 4;   // 4 rows
    int tc = (tid >> 4) * 4;   // 4 cols
    float acc[4][4] = {};
#pragma unroll 8
    for (int k = 0; k < K; ++k) {
        float4 xv = *(const float4*)&Xs[k][tr];
        float4 wv = *(const float4*)&Ws[k * 64 + tc];
        acc[0][0] += xv.x * wv.x; acc[0][1] += xv.x * wv.y; acc[0][2] += xv.x * wv.z; acc[0][3] += xv.x * wv.w;
        acc[1][0] += xv.y * wv.x; acc[1][1] += xv.y * wv.y; acc[1][2] += xv.y * wv.z; acc[1][3] += xv.y * wv.w;
        acc[2][0] += xv.z * wv.x; acc[2][1] += xv.z * wv.y; acc[2][2] += xv.z * wv.z; acc[2][3] += xv.z * wv.w;
        acc[3][0] += xv.w * wv.x; acc[3][1] += xv.w * wv.y; acc[3][2] += xv.w * wv.z; acc[3][3] += xv.w * wv.w;
    }
#pragma unroll
    for (int r = 0; r < 4; ++r) {
        int gr = row0 + tr + r;
        if (gr < M) {
            float4 o = make_float4(acc[r][0], acc[r][1], acc[r][2], acc[r][3]);
            *(float4*)&Y[gr * 64 + tc] = o;
        }
    }
}

// ---------------- 64x64 weight collapse: OutW = A @ Wd1[brow0:brow0+64,:], outc = bvec @ slice (+ addb) ----------------
__global__ __launch_bounds__(256) void wcollapse(
    const float* __restrict__ A, const float* __restrict__ Wd1, int brow0,
    const float* __restrict__ bvec, const float* __restrict__ addb,
    float* __restrict__ OutW, float* __restrict__ outc)
{
    __shared__ float As[64 * 64], Bs[64 * 64];
    int tid = threadIdx.x;
    for (int i = tid; i < 4096; i += 256) {
        As[i] = A[i];
        Bs[i] = Wd1[(brow0 + (i >> 6)) * 64 + (i & 63)];
    }
    __syncthreads();
    int r = tid >> 2, c0 = (tid & 3) * 16;
    float acc[16] = {};
    for (int k = 0; k < 64; ++k) {
        float a = As[r * 64 + k];
        const float* bp = &Bs[k * 64 + c0];
#pragma unroll
        for (int j = 0; j < 16; ++j) acc[j] += a * bp[j];
    }
#pragma unroll
    for (int j = 0; j < 16; ++j) OutW[r * 64 + c0 + j] = acc[j];
    if (tid < 64) {
        float s = addb ? addb[tid] : 0.f;
        for (int k = 0; k < 64; ++k) s += bvec[k] * Bs[k * 64 + tid];
        outc[tid] = s;
    }
}

// ---------------- CSR mean-aggregate + bias-vec + self-term (+relu) ----------------
// out[n, lane] = relu?( mean_{p in [off[n],off[n+1])} a[csr[p], lane] + bias[lane] + c[n, lane] )
__global__ __launch_bounds__(256) void agg_kernel(
    const float* __restrict__ a, const float* __restrict__ c,
    const float* __restrict__ bias,
    const int* __restrict__ off, const int* __restrict__ csr,
    float* __restrict__ out, int n_dst, int do_relu)
{
    int node = blockIdx.x * 4 + (threadIdx.x >> 6);
    if (node >= n_dst) return;
    int lane = threadIdx.x & 63;
    int beg = off[node], end = off[node + 1];
    float acc = 0.f;
    int p = beg;
    for (; p + 4 <= end; p += 4) {
        int s0 = csr[p], s1 = csr[p + 1], s2 = csr[p + 2], s3 = csr[p + 3];
        acc += a[(size_t)s0 * 64 + lane];
        acc += a[(size_t)s1 * 64 + lane];
        acc += a[(size_t)s2 * 64 + lane];
        acc += a[(size_t)s3 * 64 + lane];
    }
    for (; p < end; ++p) acc += a[(size_t)csr[p] * 64 + lane];
    int deg = end - beg;
    float inv = 1.f / (float)(deg > 0 ? deg : 1);
    float v = acc * inv + bias[lane] + c[(size_t)node * 64 + lane];
    if (do_relu) v = fmaxf(v, 0.f);
    out[(size_t)node * 64 + lane] = v;
}

// ---------------- edge decoder: out[e] = bd2 + sum_lane relu(Au[ls[e]]+Am[ld[e]]) * Wd2 ----------------
__global__ __launch_bounds__(256) void edge_dec(
    const float* __restrict__ Au, const float* __restrict__ Am,
    const int* __restrict__ ls, const int* __restrict__ ld,
    const float* __restrict__ Wd2, const float* __restrict__ bd2,
    float* __restrict__ out, int L)
{
    int e = blockIdx.x * 4 + (threadIdx.x >> 6);
    if (e >= L) return;
    int lane = threadIdx.x & 63;
    float v = Au[(size_t)ls[e] * 64 + lane] + Am[(size_t)ld[e] * 64 + lane];
    v = fmaxf(v, 0.f) * Wd2[lane];
#pragma unroll
    for (int m = 32; m >= 1; m >>= 1) v += __shfl_xor(v, m, 64);
    if (lane == 0) out[e] = v + bd2[0];
}

// ---------------- host launcher ----------------
extern "C" void kernel_launch(void* const* d_in, const int* in_sizes, int n_in,
                              void* d_out, int out_size, void* d_ws, size_t ws_size,
                              hipStream_t stream)
{
    const float* x_user  = (const float*)d_in[0];
    const float* x_movie = (const float*)d_in[1];
    const int*   esrc    = (const int*)d_in[2];
    const int*   edst    = (const int*)d_in[3];
    const int*   lsrc    = (const int*)d_in[4];
    const int*   ldst    = (const int*)d_in[5];
    const float* W1ul = (const float*)d_in[6];
    const float* b1u  = (const float*)d_in[7];
    const float* W1ur = (const float*)d_in[8];
    const float* W1ml = (const float*)d_in[9];
    const float* b1m  = (const float*)d_in[10];
    const float* W1mr = (const float*)d_in[11];
    const float* W2ul = (const float*)d_in[12];
    const float* b2u  = (const float*)d_in[13];
    const float* W2ur = (const float*)d_in[14];
    const float* W2ml = (const float*)d_in[15];
    const float* b2m  = (const float*)d_in[16];
    const float* W2mr = (const float*)d_in[17];
    const float* Wd1  = (const float*)d_in[18];
    const float* bd1  = (const float*)d_in[19];
    const float* Wd2  = (const float*)d_in[20];
    const float* bd2  = (const float*)d_in[21];
    float* out = (float*)d_out;

    const int NU = in_sizes[0] / 128;
    const int NM = in_sizes[1] / 128;
    const int E  = in_sizes[2];
    const int L  = in_sizes[4];

    // workspace layout (all offsets 256B-aligned)
    char* ws = (char*)d_ws;
    const size_t SU = (size_t)NU * 64 * 4;   // 51.2 MB
    const size_t SM = (size_t)NM * 64 * 4;   // 20.48 MB
    float* U0 = (float*)(ws + 0);
    float* U1 = (float*)(ws + SU);
    float* U2 = (float*)(ws + 2 * SU);
    float* M0 = (float*)(ws + 3 * SU);
    float* M1 = (float*)(ws + 3 * SU + SM);
    float* M2 = (float*)(ws + 3 * SU + 2 * SM);
    size_t o = 3 * SU + 3 * SM;
    auto align256 = [](size_t x) { return (x + 255) & ~(size_t)255; };
    int* off_u = (int*)(ws + o); o = align256(o + (size_t)(NU + 1) * 4);
    int* off_m = (int*)(ws + o); o = align256(o + (size_t)(NM + 1) * 4);
    int* deg_u = (int*)(ws + o); o = align256(o + (size_t)NU * 4);
    int* deg_m = (int*)(ws + o); o = align256(o + (size_t)NM * 4);
    int* cur_u = (int*)(ws + o); o = align256(o + (size_t)NU * 4);
    int* cur_m = (int*)(ws + o); o = align256(o + (size_t)NM * 4);
    int* bsum  = (int*)(ws + o); o = align256(o + 4096);
    int* csr_m_src = (int*)(ws + o); o = align256(o + (size_t)E * 4);
    int* csr_u_dst = (int*)(ws + o); o = align256(o + (size_t)E * 4);
    float* Wxu = (float*)(ws + o); o = align256(o + 4096 * 4);  // W2ml @ Wd1_top
    float* Wyu = (float*)(ws + o); o = align256(o + 4096 * 4);  // W2mr @ Wd1_top
    float* Wxm = (float*)(ws + o); o = align256(o + 4096 * 4);  // W2ul @ Wd1_bot
    float* Wym = (float*)(ws + o); o = align256(o + 4096 * 4);  // W2ur @ Wd1_bot
    float* cu  = (float*)(ws + o); o = align256(o + 64 * 4);    // b2m @ Wd1_top + bd1
    float* cm  = (float*)(ws + o); o = align256(o + 64 * 4);    // b2u @ Wd1_bot

    // ---- CSR build ----
    hipMemsetAsync(deg_u, 0, (size_t)NU * 4, stream);
    hipMemsetAsync(deg_m, 0, (size_t)NM * 4, stream);
    hipMemsetAsync(cur_u, 0, (size_t)NU * 4, stream);
    hipMemsetAsync(cur_m, 0, (size_t)NM * 4, stream);
    int egrid = (E + 255) / 256;
    hist_kernel<<<egrid, 256, 0, stream>>>(esrc, edst, E, deg_u, deg_m);

    int nb_u = (NU + 255) / 256;
    scan_k1<<<nb_u, 256, 0, stream>>>(deg_u, NU, bsum);
    scan_k2<<<1, 1024, 0, stream>>>(bsum, nb_u);
    scan_k3<<<nb_u, 256, 0, stream>>>(deg_u, NU, bsum, off_u);

    int nb_m = (NM + 255) / 256;
    scan_k1<<<nb_m, 256, 0, stream>>>(deg_m, NM, bsum);
    scan_k2<<<1, 1024, 0, stream>>>(bsum, nb_m);
    scan_k3<<<nb_m, 256, 0, stream>>>(deg_m, NM, bsum, off_m);

    place_kernel<<<egrid, 256, 0, stream>>>(esrc, edst, E, off_m, cur_m, csr_m_src,
                                            off_u, cur_u, csr_u_dst);

    // ---- decoder weight collapse (tiny) ----
    wcollapse<<<1, 256, 0, stream>>>(W2ml, Wd1, 0,  b2m, bd1,     Wxu, cu);
    wcollapse<<<1, 256, 0, stream>>>(W2mr, Wd1, 0,  b2m, nullptr, Wyu, cu);  // cu overwritten below? no:
    // NOTE: second call writes outc=cu again with wrong value — give it a scratch target instead.
    // (fixed below by re-running the correct one last)
    wcollapse<<<1, 256, 0, stream>>>(W2ul, Wd1, 64, b2u, nullptr, Wxm, cm);
    wcollapse<<<1, 256, 0, stream>>>(W2ur, Wd1, 64, b2u, nullptr, Wym, cm);
    // re-establish correct bias vectors (cheap, deterministic):
    wcollapse<<<1, 256, 0, stream>>>(W2ml, Wd1, 0,  b2m, bd1,     Wxu, cu);
    wcollapse<<<1, 256, 0, stream>>>(W2ul, Wd1, 64, b2u, nullptr, Wxm, cm);

    int gu = (NU + 63) / 64, gm = (NM + 63) / 64;

    // ---- layer 1: pre-multiplied tables + self terms ----
    gemm_tile<128><<<gu, 256, 0, stream>>>(x_user,  W1ul, U0, NU);  // gathered by movie agg
    gemm_tile<128><<<gu, 256, 0, stream>>>(x_user,  W1mr, U1, NU);  // self term for h_u
    gemm_tile<128><<<gm, 256, 0, stream>>>(x_movie, W1ml, M0, NM);  // gathered by user agg
    gemm_tile<128><<<gm, 256, 0, stream>>>(x_movie, W1ur, M1, NM);  // self term for h_m

    int agm = (NM + 3) / 4, agu = (NU + 3) / 4;
    agg_kernel<<<agm, 256, 0, stream>>>(U0, M1, b1u, off_m, csr_m_src, M2, NM, 1); // h_m
    agg_kernel<<<agu, 256, 0, stream>>>(M0, U1, b1m, off_u, csr_u_dst, U2, NU, 1); // h_u

    // ---- layer 2 with decoder-collapsed weights ----
    gemm_tile<64><<<gm, 256, 0, stream>>>(M2, Wxu, M0, NM);  // G_m = h_m @ (W2ml Wd1_top), gathered by user agg
    gemm_tile<64><<<gu, 256, 0, stream>>>(U2, Wyu, U0, NU);  // S_u = h_u @ (W2mr Wd1_top), self term for Au
    gemm_tile<64><<<gu, 256, 0, stream>>>(U2, Wxm, U1, NU);  // G_u = h_u @ (W2ul Wd1_bot), gathered by movie agg
    gemm_tile<64><<<gm, 256, 0, stream>>>(M2, Wym, M1, NM);  // S_m = h_m @ (W2ur Wd1_bot), self term for Am

    agg_kernel<<<agu, 256, 0, stream>>>(M0, U0, cu, off_u, csr_u_dst, U2, NU, 0); // Au (overwrites h_u)
    agg_kernel<<<agm, 256, 0, stream>>>(U1, M1, cm, off_m, csr_m_src, M2, NM, 0); // Am (overwrites h_m)

    // ---- edge decoder ----
    int gl = (L + 3) / 4;
    edge_dec<<<gl, 256, 0, stream>>>(U2, M2, lsrc, ldst, Wd2, bd2, out, L);
}